// Round 2
// baseline (1153.822 us; speedup 1.0000x reference)
//
#include <hip/hip_runtime.h>
#include <math.h>

// Problem constants (fixed by the reference)
#define NHEADS 8
#define HDIM   128
#define WIN    16
#define DIM    1024
#define SEQ    2048
#define BATCH  4
#define MROWS  (BATCH * SEQ)   // 8192
#define RMS_EPS 1e-6f

// ---------------- GEMM (NT): C[M,N] = A[M,K] * B[N,K]^T, all fp32 ----------------
// 64x64 tile, BK=16, 256 threads, 4x4 micro-tile per thread.
// LDS stored k-major, leading dim 68 (pad) -> reads are broadcast/conflict-light.
__global__ __launch_bounds__(256) void gemm_nt(const float* __restrict__ A,
                                               const float* __restrict__ B,
                                               float* __restrict__ C,
                                               int M, int N, int K)
{
    __shared__ float As[16][68];
    __shared__ float Bs[16][68];

    const int t   = threadIdx.x;
    const int tx  = t & 15;        // 0..15 (N direction)
    const int ty  = t >> 4;        // 0..15 (M direction)
    const int bn0 = blockIdx.x * 64;
    const int bm0 = blockIdx.y * 64;

    // staging: each thread loads one 4-elem strip of the 64x16 A tile and B tile
    const int lrow = t >> 2;       // 0..63
    const int lc4  = t & 3;        // 0..3

    const float* aptr = A + (size_t)(bm0 + lrow) * K + lc4 * 4;
    const float* bptr = B + (size_t)(bn0 + lrow) * K + lc4 * 4;

    float acc[4][4] = {};

    for (int kt = 0; kt < K; kt += 16) {
        const float4 av = *(const float4*)(aptr + kt);
        const float4 bv = *(const float4*)(bptr + kt);
        __syncthreads();           // previous tile's compute done before overwrite
        As[lc4 * 4 + 0][lrow] = av.x; As[lc4 * 4 + 1][lrow] = av.y;
        As[lc4 * 4 + 2][lrow] = av.z; As[lc4 * 4 + 3][lrow] = av.w;
        Bs[lc4 * 4 + 0][lrow] = bv.x; Bs[lc4 * 4 + 1][lrow] = bv.y;
        Bs[lc4 * 4 + 2][lrow] = bv.z; Bs[lc4 * 4 + 3][lrow] = bv.w;
        __syncthreads();
        #pragma unroll
        for (int kk = 0; kk < 16; ++kk) {
            float a[4], b[4];
            #pragma unroll
            for (int i = 0; i < 4; ++i) a[i] = As[kk][ty * 4 + i];
            #pragma unroll
            for (int j = 0; j < 4; ++j) b[j] = Bs[kk][tx * 4 + j];
            #pragma unroll
            for (int i = 0; i < 4; ++i)
                #pragma unroll
                for (int j = 0; j < 4; ++j)
                    acc[i][j] = fmaf(a[i], b[j], acc[i][j]);
        }
    }

    #pragma unroll
    for (int i = 0; i < 4; ++i) {
        float* crow = C + (size_t)(bm0 + ty * 4 + i) * N + bn0 + tx * 4;
        #pragma unroll
        for (int j = 0; j < 4; ++j) crow[j] = acc[i][j];
    }
}

// ---------------- RMSNorm over last dim (1024), in place, fp32 ----------------
// one 256-thread block per row; 4 floats per thread
__global__ __launch_bounds__(256) void rmsnorm_kernel(float* __restrict__ x,
                                                      const float* __restrict__ w)
{
    const int row = blockIdx.x;
    const int t   = threadIdx.x;
    float* xr = x + (size_t)row * DIM;

    float4 v = ((const float4*)xr)[t];
    float ss = v.x * v.x + v.y * v.y + v.z * v.z + v.w * v.w;
    #pragma unroll
    for (int off = 32; off > 0; off >>= 1) ss += __shfl_xor(ss, off, 64);

    __shared__ float red[4];
    if ((t & 63) == 0) red[t >> 6] = ss;
    __syncthreads();
    const float total = red[0] + red[1] + red[2] + red[3];
    const float scale = rsqrtf(total * (1.0f / DIM) + RMS_EPS);

    const float4 wv = ((const float4*)w)[t];
    v.x *= scale * wv.x;
    v.y *= scale * wv.y;
    v.z *= scale * wv.z;
    v.w *= scale * wv.w;
    ((float4*)xr)[t] = v;
}

// ---------------- Sliding-window attention, one wave per (b, i, h) ----------------
// Window of <=17 keys, ALiBi bias slope_h*(j-i), softmax in registers.
// o may alias q (each wave reads only its own q slice, then writes that slice).
__global__ __launch_bounds__(256) void attn_kernel(const float* q,
                                                   const float* __restrict__ k,
                                                   const float* __restrict__ v,
                                                   float* o)
{
    const int wave = (int)((blockIdx.x * blockDim.x + threadIdx.x) >> 6);
    const int lane = threadIdx.x & 63;

    const int h  = wave & (NHEADS - 1);
    const int bi = wave >> 3;            // b*SEQ + i
    const int i  = bi & (SEQ - 1);
    const int b  = bi >> 11;
    const int base_row = b << 11;        // b*SEQ

    const size_t qoff = (size_t)(base_row + i) * DIM + h * HDIM;
    const float2 qv = ((const float2*)(q + qoff))[lane];

    const float scale = 0.088388347648318447f;   // 1/sqrt(128)
    const float slope = exp2f(-(float)(h + 1));  // ALiBi slope for head h

    float s[WIN + 1];
    #pragma unroll
    for (int jj = 0; jj <= WIN; ++jj) {
        const int j  = i - WIN + jj;
        const int jc = j < 0 ? 0 : j;
        const size_t koff = (size_t)(base_row + jc) * DIM + h * HDIM;
        const float2 kv = ((const float2*)(k + koff))[lane];
        float p = qv.x * kv.x + qv.y * kv.y;
        #pragma unroll
        for (int off = 32; off > 0; off >>= 1) p += __shfl_xor(p, off, 64);
        s[jj] = (j < 0) ? -INFINITY : (p * scale + slope * (float)(j - i));
    }

    float m = s[WIN];                 // j=i always valid
    #pragma unroll
    for (int jj = 0; jj < WIN; ++jj) m = fmaxf(m, s[jj]);
    float sum = 0.f;
    #pragma unroll
    for (int jj = 0; jj <= WIN; ++jj) { s[jj] = __expf(s[jj] - m); sum += s[jj]; }
    const float inv = 1.0f / sum;

    float2 acc = make_float2(0.f, 0.f);
    #pragma unroll
    for (int jj = 0; jj <= WIN; ++jj) {
        const int j = i - WIN + jj;
        if (j >= 0) {
            const size_t voff = (size_t)(base_row + j) * DIM + h * HDIM;
            const float2 vv = ((const float2*)(v + voff))[lane];
            const float p = s[jj] * inv;
            acc.x = fmaf(p, vv.x, acc.x);
            acc.y = fmaf(p, vv.y, acc.y);
        }
    }
    ((float2*)(o + qoff))[lane] = acc;
}

// ---------------- launch ----------------
extern "C" void kernel_launch(void* const* d_in, const int* in_sizes, int n_in,
                              void* d_out, int out_size, void* d_ws, size_t ws_size,
                              hipStream_t stream)
{
    const float* x  = (const float*)d_in[0];
    const float* wq = (const float*)d_in[1];
    const float* wk = (const float*)d_in[2];
    const float* wv = (const float*)d_in[3];
    const float* wo = (const float*)d_in[4];
    const float* qw = (const float*)d_in[5];
    const float* kw = (const float*)d_in[6];
    float* out = (float*)d_out;

    // fp32 workspace: xq | xk | xv  (3 * 32 MB = 96 MB). ctx is written
    // in-place over xq by attn_kernel (safe: each wave reads only its own q slice).
    float* xq = (float*)d_ws;
    float* xk = xq + (size_t)MROWS * DIM;
    float* xv = xk + (size_t)MROWS * DIM;

    dim3 g(DIM / 64, MROWS / 64);
    gemm_nt<<<g, 256, 0, stream>>>(x, wq, xq, MROWS, DIM, DIM);
    gemm_nt<<<g, 256, 0, stream>>>(x, wk, xk, MROWS, DIM, DIM);
    gemm_nt<<<g, 256, 0, stream>>>(x, wv, xv, MROWS, DIM, DIM);
    rmsnorm_kernel<<<MROWS, 256, 0, stream>>>(xq, qw);
    rmsnorm_kernel<<<MROWS, 256, 0, stream>>>(xk, kw);
    attn_kernel<<<(BATCH * SEQ * NHEADS) / 4, 256, 0, stream>>>(xq, xk, xv, xq);
    gemm_nt<<<g, 256, 0, stream>>>(xq, wo, out, MROWS, DIM, DIM);
}

// Round 3
// 320.549 us; speedup vs baseline: 3.5995x; 3.5995x over previous
//
#include <hip/hip_runtime.h>
#include <math.h>

// Problem constants (fixed by the reference)
#define NHEADS 8
#define HDIM   128
#define WIN    16
#define DIM    1024
#define SEQ    2048
#define BATCH  4
#define MROWS  (BATCH * SEQ)   // 8192
#define RMS_EPS 1e-6f

typedef __bf16 bf16x8 __attribute__((ext_vector_type(8)));
typedef float  f32x4  __attribute__((ext_vector_type(4)));

// ---------------- bf16 bit helpers (RNE) ----------------
__device__ __forceinline__ unsigned short f2b(float f) {
    union { float f; unsigned u; } c; c.f = f;
    return (unsigned short)((c.u + 0x7FFFu + ((c.u >> 16) & 1u)) >> 16);
}
__device__ __forceinline__ float b2f(unsigned short u) {
    union { unsigned u; float f; } c; c.u = ((unsigned)u) << 16; return c.f;
}

__device__ __forceinline__ void storec(unsigned short* p, float v) { *p = f2b(v); }
__device__ __forceinline__ void storec(float* p, float v) { *p = v; }

// ---------------- cast kernels ----------------
__global__ __launch_bounds__(256) void cast_f32_bf16(const float* __restrict__ src,
                                                     unsigned short* __restrict__ dst, int n4)
{
    const int i = blockIdx.x * 256 + threadIdx.x;
    if (i < n4) {
        const float4 v = ((const float4*)src)[i];
        ushort4 o;
        o.x = f2b(v.x); o.y = f2b(v.y); o.z = f2b(v.z); o.w = f2b(v.w);
        ((ushort4*)dst)[i] = o;
    }
}

// four 1024x1024 weights -> contiguous bf16 at dst (+ which*DIM*DIM)
__global__ __launch_bounds__(256) void cast_weights(const float* __restrict__ s0,
                                                    const float* __restrict__ s1,
                                                    const float* __restrict__ s2,
                                                    const float* __restrict__ s3,
                                                    unsigned short* __restrict__ dst)
{
    const int b = blockIdx.x;
    const int which = b >> 10;           // 1024 blocks per weight (1M elems / 4 / 256)
    const int i = (b & 1023) * 256 + threadIdx.x;
    const float* s = which == 0 ? s0 : which == 1 ? s1 : which == 2 ? s2 : s3;
    const float4 v = ((const float4*)s)[i];
    ushort4 o;
    o.x = f2b(v.x); o.y = f2b(v.y); o.z = f2b(v.z); o.w = f2b(v.w);
    ((ushort4*)(dst + (size_t)which * DIM * DIM))[i] = o;
}

// ---------------- MFMA GEMM (NT): C[M,N] = A[M,K] * B[N,K]^T, bf16 in, fp32 acc ----------------
// m97-ladder structure: 128x128 tile, BK=32, 256 threads = 4 waves, each wave 64x64
// (4x4 grid of 16x16x32 MFMAs). Staging via global_load_lds width=16 (wave-uniform
// LDS base + lane*16B: one instr covers 16 rows of the row-major [128][32] tile).
template <typename TC>
__global__ __launch_bounds__(256) void gemm_nt_mfma(const unsigned short* __restrict__ A,
                                                    const unsigned short* __restrict__ B,
                                                    TC* __restrict__ C,
                                                    int M, int N, int K)
{
    __shared__ __align__(16) __bf16 As[128 * 32];
    __shared__ __align__(16) __bf16 Bs[128 * 32];

    const int t    = threadIdx.x;
    const int w    = t >> 6;          // wave 0..3
    const int lane = t & 63;
    const int wm   = w >> 1;          // wave row (0..1)
    const int wn   = w & 1;           // wave col (0..1)
    const int bm0  = blockIdx.y * 128;
    const int bn0  = blockIdx.x * 128;

    // staging: wave w covers row-segments {w, w+4} of the 8x16-row tile.
    // lane l -> row (l>>2) within segment, k-chunk (l&3)*8  (matches LDS base + l*16B)
    const int sr = lane >> 2;
    const int kc = (lane & 3) * 8;

    const unsigned short* gA0 = A + (size_t)(bm0 + w * 16 + sr) * K + kc;
    const unsigned short* gA1 = gA0 + (size_t)64 * K;
    const unsigned short* gB0 = B + (size_t)(bn0 + w * 16 + sr) * K + kc;
    const unsigned short* gB1 = gB0 + (size_t)64 * K;

    __bf16* lA0 = &As[(w * 16) * 32];        // wave-uniform LDS bases
    __bf16* lA1 = &As[(w * 16 + 64) * 32];
    __bf16* lB0 = &Bs[(w * 16) * 32];
    __bf16* lB1 = &Bs[(w * 16 + 64) * 32];

    // fragment read coords: A[m=lane&15][k=(lane>>4)*8+j], B likewise (NT)
    const int frow = lane & 15;
    const int fk   = (lane >> 4) * 8;

    f32x4 acc[4][4];
    #pragma unroll
    for (int i = 0; i < 4; ++i)
        #pragma unroll
        for (int j = 0; j < 4; ++j)
            #pragma unroll
            for (int e = 0; e < 4; ++e) acc[i][j][e] = 0.f;

    for (int kt = 0; kt < K; kt += 32) {
        __syncthreads();   // previous iteration's ds_reads retired before overwrite
        __builtin_amdgcn_global_load_lds((const __attribute__((address_space(1))) void*)(gA0 + kt),
                                         (__attribute__((address_space(3))) void*)lA0, 16, 0, 0);
        __builtin_amdgcn_global_load_lds((const __attribute__((address_space(1))) void*)(gA1 + kt),
                                         (__attribute__((address_space(3))) void*)lA1, 16, 0, 0);
        __builtin_amdgcn_global_load_lds((const __attribute__((address_space(1))) void*)(gB0 + kt),
                                         (__attribute__((address_space(3))) void*)lB0, 16, 0, 0);
        __builtin_amdgcn_global_load_lds((const __attribute__((address_space(1))) void*)(gB1 + kt),
                                         (__attribute__((address_space(3))) void*)lB1, 16, 0, 0);
        __syncthreads();   // drains vmcnt: tile resident

        bf16x8 af[4], bg[4];
        #pragma unroll
        for (int i = 0; i < 4; ++i) {
            af[i] = *(const bf16x8*)&As[(wm * 64 + i * 16 + frow) * 32 + fk];
            bg[i] = *(const bf16x8*)&Bs[(wn * 64 + i * 16 + frow) * 32 + fk];
        }
        #pragma unroll
        for (int i = 0; i < 4; ++i)
            #pragma unroll
            for (int j = 0; j < 4; ++j)
                acc[i][j] = __builtin_amdgcn_mfma_f32_16x16x32_bf16(af[i], bg[j], acc[i][j], 0, 0, 0);
    }

    // epilogue: C/D layout col=lane&15, row=(lane>>4)*4+reg  [m89-verified]
    const int m_base = bm0 + wm * 64;
    const int n_base = bn0 + wn * 64;
    const int col    = lane & 15;
    const int rquad  = (lane >> 4) * 4;
    #pragma unroll
    for (int i = 0; i < 4; ++i)
        #pragma unroll
        for (int r = 0; r < 4; ++r) {
            TC* crow = C + (size_t)(m_base + i * 16 + rquad + r) * N + n_base + col;
            #pragma unroll
            for (int j = 0; j < 4; ++j)
                storec(crow + j * 16, acc[i][j][r]);
        }
}

// ---------------- RMSNorm over last dim (1024), bf16 in/out, fp32 math ----------------
__global__ __launch_bounds__(256) void rmsnorm_bf16(unsigned short* __restrict__ x,
                                                    const float* __restrict__ w)
{
    const int row = blockIdx.x;
    const int t   = threadIdx.x;
    unsigned short* xr = x + (size_t)row * DIM;

    const ushort4 u = ((const ushort4*)xr)[t];
    const float4 v = make_float4(b2f(u.x), b2f(u.y), b2f(u.z), b2f(u.w));
    float ss = v.x * v.x + v.y * v.y + v.z * v.z + v.w * v.w;
    #pragma unroll
    for (int off = 32; off > 0; off >>= 1) ss += __shfl_xor(ss, off, 64);

    __shared__ float red[4];
    if ((t & 63) == 0) red[t >> 6] = ss;
    __syncthreads();
    const float total = red[0] + red[1] + red[2] + red[3];
    const float scale = rsqrtf(total * (1.0f / DIM) + RMS_EPS);

    const float4 wv = ((const float4*)w)[t];
    ushort4 o;
    o.x = f2b(v.x * scale * wv.x);
    o.y = f2b(v.y * scale * wv.y);
    o.z = f2b(v.z * scale * wv.z);
    o.w = f2b(v.w * scale * wv.w);
    ((ushort4*)xr)[t] = o;
}

// ---------------- Sliding-window attention, one wave per (b, i, h), bf16 I/O ----------------
__global__ __launch_bounds__(256) void attn_bf16(const unsigned short* q,
                                                 const unsigned short* __restrict__ k,
                                                 const unsigned short* __restrict__ v,
                                                 unsigned short* o)
{
    const int wave = (int)((blockIdx.x * blockDim.x + threadIdx.x) >> 6);
    const int lane = threadIdx.x & 63;

    const int h  = wave & (NHEADS - 1);
    const int bi = wave >> 3;            // b*SEQ + i
    const int i  = bi & (SEQ - 1);
    const int b  = bi >> 11;
    const int base_row = b << 11;        // b*SEQ

    const size_t qoff = (size_t)(base_row + i) * DIM + h * HDIM;
    const unsigned qu = ((const unsigned*)(q + qoff))[lane];
    const float qx = b2f((unsigned short)(qu & 0xFFFFu));
    const float qy = b2f((unsigned short)(qu >> 16));

    const float scale = 0.088388347648318447f;   // 1/sqrt(128)
    const float slope = exp2f(-(float)(h + 1));  // ALiBi slope for head h

    float s[WIN + 1];
    #pragma unroll
    for (int jj = 0; jj <= WIN; ++jj) {
        const int j  = i - WIN + jj;
        const int jc = j < 0 ? 0 : j;
        const size_t koff = (size_t)(base_row + jc) * DIM + h * HDIM;
        const unsigned ku = ((const unsigned*)(k + koff))[lane];
        float p = qx * b2f((unsigned short)(ku & 0xFFFFu)) + qy * b2f((unsigned short)(ku >> 16));
        #pragma unroll
        for (int off = 32; off > 0; off >>= 1) p += __shfl_xor(p, off, 64);
        s[jj] = (j < 0) ? -INFINITY : (p * scale + slope * (float)(j - i));
    }

    float m = s[WIN];                 // j=i always valid
    #pragma unroll
    for (int jj = 0; jj < WIN; ++jj) m = fmaxf(m, s[jj]);
    float sum = 0.f;
    #pragma unroll
    for (int jj = 0; jj <= WIN; ++jj) { s[jj] = __expf(s[jj] - m); sum += s[jj]; }
    const float inv = 1.0f / sum;

    float ax = 0.f, ay = 0.f;
    #pragma unroll
    for (int jj = 0; jj <= WIN; ++jj) {
        const int j = i - WIN + jj;
        if (j >= 0) {
            const size_t voff = (size_t)(base_row + j) * DIM + h * HDIM;
            const unsigned vu = ((const unsigned*)(v + voff))[lane];
            const float p = s[jj] * inv;
            ax = fmaf(p, b2f((unsigned short)(vu & 0xFFFFu)), ax);
            ay = fmaf(p, b2f((unsigned short)(vu >> 16)), ay);
        }
    }
    const unsigned ou = (unsigned)f2b(ax) | ((unsigned)f2b(ay) << 16);
    ((unsigned*)(o + qoff))[lane] = ou;
}

// ---------------- launch ----------------
extern "C" void kernel_launch(void* const* d_in, const int* in_sizes, int n_in,
                              void* d_out, int out_size, void* d_ws, size_t ws_size,
                              hipStream_t stream)
{
    const float* x  = (const float*)d_in[0];
    const float* wq = (const float*)d_in[1];
    const float* wk = (const float*)d_in[2];
    const float* wv = (const float*)d_in[3];
    const float* wo = (const float*)d_in[4];
    const float* qw = (const float*)d_in[5];
    const float* kw = (const float*)d_in[6];
    float* out = (float*)d_out;

    // bf16 workspace (72 MB total; 96 MB proven available in round 2):
    // xb[8192x1024] | wqb|wkb|wvb|wob [1024x1024 each] | xq | xk | xv [8192x1024 each]
    unsigned short* xb  = (unsigned short*)d_ws;
    unsigned short* wqb = xb  + (size_t)MROWS * DIM;
    unsigned short* wkb = wqb + (size_t)DIM * DIM;
    unsigned short* wvb = wkb + (size_t)DIM * DIM;
    unsigned short* wob = wvb + (size_t)DIM * DIM;
    unsigned short* xq  = wob + (size_t)DIM * DIM;
    unsigned short* xk  = xq  + (size_t)MROWS * DIM;
    unsigned short* xv  = xk  + (size_t)MROWS * DIM;

    cast_f32_bf16<<<(MROWS * DIM / 4 + 255) / 256, 256, 0, stream>>>(x, xb, MROWS * DIM / 4);
    cast_weights<<<4096, 256, 0, stream>>>(wq, wk, wv, wo, wqb);

    dim3 g(DIM / 128, MROWS / 128);   // (8, 64)
    gemm_nt_mfma<unsigned short><<<g, 256, 0, stream>>>(xb, wqb, xq, MROWS, DIM, DIM);
    gemm_nt_mfma<unsigned short><<<g, 256, 0, stream>>>(xb, wkb, xk, MROWS, DIM, DIM);
    gemm_nt_mfma<unsigned short><<<g, 256, 0, stream>>>(xb, wvb, xv, MROWS, DIM, DIM);
    rmsnorm_bf16<<<MROWS, 256, 0, stream>>>(xq, qw);
    rmsnorm_bf16<<<MROWS, 256, 0, stream>>>(xk, kw);
    attn_bf16<<<(BATCH * SEQ * NHEADS) / 4, 256, 0, stream>>>(xq, xk, xv, xq);
    gemm_nt_mfma<float><<<g, 256, 0, stream>>>(xq, wob, out, MROWS, DIM, DIM);
}

// Round 4
// 229.443 us; speedup vs baseline: 5.0288x; 1.3971x over previous
//
#include <hip/hip_runtime.h>
#include <math.h>

// Problem constants (fixed by the reference)
#define NHEADS 8
#define HDIM   128
#define WIN    16
#define DIM    1024
#define QKVDIM 3072
#define SEQ    2048
#define BATCH  4
#define MROWS  (BATCH * SEQ)   // 8192
#define RMS_EPS 1e-6f

typedef __bf16 bf16x8 __attribute__((ext_vector_type(8)));
typedef unsigned short u16x8 __attribute__((ext_vector_type(8)));
typedef float  f32x4  __attribute__((ext_vector_type(4)));

// ---------------- bf16 bit helpers (RNE) ----------------
__device__ __forceinline__ unsigned short f2b(float f) {
    union { float f; unsigned u; } c; c.f = f;
    return (unsigned short)((c.u + 0x7FFFu + ((c.u >> 16) & 1u)) >> 16);
}
__device__ __forceinline__ float b2f(unsigned short u) {
    union { unsigned u; float f; } c; c.u = ((unsigned)u) << 16; return c.f;
}

__device__ __forceinline__ void storec(unsigned short* p, float v) { *p = f2b(v); }
__device__ __forceinline__ void storec(float* p, float v) { *p = v; }

// ---------------- fused cast: x (8192x1024) + 4 weights (1024x1024 each) ----------------
// blocks 0..8191: x -> xb. blocks 8192..12287: weights -> wb (contiguous wq|wk|wv|wo)
__global__ __launch_bounds__(256) void cast_all(const float* __restrict__ x,
                                                const float* __restrict__ w0,
                                                const float* __restrict__ w1,
                                                const float* __restrict__ w2,
                                                const float* __restrict__ w3,
                                                unsigned short* __restrict__ xb,
                                                unsigned short* __restrict__ wb)
{
    const int b = blockIdx.x;
    const int t = threadIdx.x;
    const float* src;
    unsigned short* dst;
    int i;
    if (b < 8192) {
        i = b * 256 + t;
        src = x; dst = xb;
    } else {
        const int bb = b - 8192;
        const int which = bb >> 10;
        i = (bb & 1023) * 256 + t;
        src = which == 0 ? w0 : which == 1 ? w1 : which == 2 ? w2 : w3;
        dst = wb + (size_t)which * DIM * DIM;
    }
    const float4 v = ((const float4*)src)[i];
    ushort4 o;
    o.x = f2b(v.x); o.y = f2b(v.y); o.z = f2b(v.z); o.w = f2b(v.w);
    ((ushort4*)dst)[i] = o;
}

// ---------------- MFMA GEMM (NT): C[M,N] = A[M,K] * B[N,K]^T, bf16 in, fp32 acc ----------------
template <typename TC>
__global__ __launch_bounds__(256) void gemm_nt_mfma(const unsigned short* __restrict__ A,
                                                    const unsigned short* __restrict__ B,
                                                    TC* __restrict__ C,
                                                    int M, int N, int K)
{
    __shared__ __align__(16) __bf16 As[128 * 32];
    __shared__ __align__(16) __bf16 Bs[128 * 32];

    const int t    = threadIdx.x;
    const int w    = t >> 6;
    const int lane = t & 63;
    const int wm   = w >> 1;
    const int wn   = w & 1;
    const int bm0  = blockIdx.y * 128;
    const int bn0  = blockIdx.x * 128;

    const int sr = lane >> 2;
    const int kc = (lane & 3) * 8;

    const unsigned short* gA0 = A + (size_t)(bm0 + w * 16 + sr) * K + kc;
    const unsigned short* gA1 = gA0 + (size_t)64 * K;
    const unsigned short* gB0 = B + (size_t)(bn0 + w * 16 + sr) * K + kc;
    const unsigned short* gB1 = gB0 + (size_t)64 * K;

    __bf16* lA0 = &As[(w * 16) * 32];
    __bf16* lA1 = &As[(w * 16 + 64) * 32];
    __bf16* lB0 = &Bs[(w * 16) * 32];
    __bf16* lB1 = &Bs[(w * 16 + 64) * 32];

    const int frow = lane & 15;
    const int fk   = (lane >> 4) * 8;

    f32x4 acc[4][4];
    #pragma unroll
    for (int i = 0; i < 4; ++i)
        #pragma unroll
        for (int j = 0; j < 4; ++j)
            #pragma unroll
            for (int e = 0; e < 4; ++e) acc[i][j][e] = 0.f;

    for (int kt = 0; kt < K; kt += 32) {
        __syncthreads();
        __builtin_amdgcn_global_load_lds((const __attribute__((address_space(1))) void*)(gA0 + kt),
                                         (__attribute__((address_space(3))) void*)lA0, 16, 0, 0);
        __builtin_amdgcn_global_load_lds((const __attribute__((address_space(1))) void*)(gA1 + kt),
                                         (__attribute__((address_space(3))) void*)lA1, 16, 0, 0);
        __builtin_amdgcn_global_load_lds((const __attribute__((address_space(1))) void*)(gB0 + kt),
                                         (__attribute__((address_space(3))) void*)lB0, 16, 0, 0);
        __builtin_amdgcn_global_load_lds((const __attribute__((address_space(1))) void*)(gB1 + kt),
                                         (__attribute__((address_space(3))) void*)lB1, 16, 0, 0);
        __syncthreads();

        bf16x8 af[4], bg[4];
        #pragma unroll
        for (int i = 0; i < 4; ++i) {
            af[i] = *(const bf16x8*)&As[(wm * 64 + i * 16 + frow) * 32 + fk];
            bg[i] = *(const bf16x8*)&Bs[(wn * 64 + i * 16 + frow) * 32 + fk];
        }
        #pragma unroll
        for (int i = 0; i < 4; ++i)
            #pragma unroll
            for (int j = 0; j < 4; ++j)
                acc[i][j] = __builtin_amdgcn_mfma_f32_16x16x32_bf16(af[i], bg[j], acc[i][j], 0, 0, 0);
    }

    const int m_base = bm0 + wm * 64;
    const int n_base = bn0 + wn * 64;
    const int col    = lane & 15;
    const int rquad  = (lane >> 4) * 4;
    #pragma unroll
    for (int i = 0; i < 4; ++i)
        #pragma unroll
        for (int r = 0; r < 4; ++r) {
            TC* crow = C + (size_t)(m_base + i * 16 + rquad + r) * N + n_base + col;
            #pragma unroll
            for (int j = 0; j < 4; ++j)
                storec(crow + j * 16, acc[i][j][r]);
        }
}

// ---------------- RMSNorm on xqkv: grid (MROWS, 2); which=0 -> q cols, 1 -> k cols ----------------
__global__ __launch_bounds__(256) void rmsnorm2(unsigned short* __restrict__ xqkv,
                                                const float* __restrict__ qw,
                                                const float* __restrict__ kw)
{
    const int row   = blockIdx.x;
    const int which = blockIdx.y;
    const int t     = threadIdx.x;
    unsigned short* xr = xqkv + (size_t)row * QKVDIM + which * DIM;
    const float* w = which ? kw : qw;

    const ushort4 u = ((const ushort4*)xr)[t];
    const float4 v = make_float4(b2f(u.x), b2f(u.y), b2f(u.z), b2f(u.w));
    float ss = v.x * v.x + v.y * v.y + v.z * v.z + v.w * v.w;
    #pragma unroll
    for (int off = 32; off > 0; off >>= 1) ss += __shfl_xor(ss, off, 64);

    __shared__ float red[4];
    if ((t & 63) == 0) red[t >> 6] = ss;
    __syncthreads();
    const float total = red[0] + red[1] + red[2] + red[3];
    const float scale = rsqrtf(total * (1.0f / DIM) + RMS_EPS);

    const float4 wv = ((const float4*)w)[t];
    ushort4 o;
    o.x = f2b(v.x * scale * wv.x);
    o.y = f2b(v.y * scale * wv.y);
    o.z = f2b(v.z * scale * wv.z);
    o.w = f2b(v.w * scale * wv.w);
    ((ushort4*)xr)[t] = o;
}

// ---------------- MFMA sliding-window attention ----------------
// grid (MROWS/64, NHEADS). Block: 64 queries x 1 head, 4 waves x 16 queries.
// Wave w: queries i0+16w..+15; keys (seq-local) i0-16+16w .. i0+15+16w (32, local lk=16w..16w+31).
// K staged natural ([key][d], pad 136), V staged transposed ([d][key], pad 88).
// S via 16x16x32 MFMA (2 key-tiles x 4 d-chunks); softmax in C-layout; P through
// wave-private LDS (C-layout -> A-layout); PV via 8 MFMAs; 1/sum at epilogue.
__global__ __launch_bounds__(256) void attn_mfma(const unsigned short* __restrict__ qkv,
                                                 unsigned short* __restrict__ o)
{
    __shared__ __align__(16) unsigned short Klds[80 * 136];
    __shared__ __align__(16) unsigned short Vt[128 * 88];
    __shared__ __align__(16) unsigned short Plds[4 * 16 * 40];

    const int t  = threadIdx.x;
    const int qb = blockIdx.x;          // 0..127
    const int h  = blockIdx.y;
    const int r0 = qb * 64;             // first query's global row
    const int i0 = r0 & (SEQ - 1);      // seq-local (block never spans batches)
    const int bb = r0 - i0;             // batch base row

    const unsigned short* kg = qkv + DIM + h * HDIM;       // K columns of xqkv
    const unsigned short* vg = qkv + 2 * DIM + h * HDIM;   // V columns

    // ---- stage: 80 rows x 128 elems for K and V (1280 16B-chunks each, 5 per thread)
    #pragma unroll
    for (int it = 0; it < 5; ++it) {
        const int c = it * 256 + t;
        {   // K: row-major chunk map (coalesced global, ~2-way LDS write)
            const int lr = c >> 4, c8 = c & 15;
            const int ks = i0 - 16 + lr;
            const int rc = ks < 0 ? 0 : ks;          // clamped rows are masked later
            const u16x8 kv = *(const u16x8*)(kg + (size_t)(bb + rc) * QKVDIM + c8 * 8);
            *(u16x8*)&Klds[lr * 136 + c8 * 8] = kv;
        }
        {   // V: key-consecutive chunk map -> near-conflict-free transposed scatter
            const int c8 = c / 80, lr = c - c8 * 80;
            const int ks = i0 - 16 + lr;
            const int rc = ks < 0 ? 0 : ks;
            const u16x8 vv = *(const u16x8*)(vg + (size_t)(bb + rc) * QKVDIM + c8 * 8);
            #pragma unroll
            for (int e = 0; e < 8; ++e)
                Vt[(c8 * 8 + e) * 88 + lr] = vv[e];
        }
    }
    __syncthreads();

    const int w    = t >> 6;
    const int lane = t & 63;
    const int frow = lane & 15;          // A/B frag row; also C-layout col
    const int quad = lane >> 4;
    const int fk   = quad * 8;           // frag k-offset

    // ---- S = Q K^T (A-frags straight from global; B-frags from Klds)
    f32x4 s0 = {0.f, 0.f, 0.f, 0.f}, s1 = {0.f, 0.f, 0.f, 0.f};
    const unsigned short* qg = qkv + h * HDIM;
    const size_t qrow = (size_t)(r0 + w * 16 + frow) * QKVDIM;
    #pragma unroll
    for (int kt = 0; kt < 4; ++kt) {
        const bf16x8 af = *(const bf16x8*)(qg + qrow + kt * 32 + fk);
        const bf16x8 b0 = *(const bf16x8*)&Klds[(w * 16 + frow) * 136 + kt * 32 + fk];
        const bf16x8 b1 = *(const bf16x8*)&Klds[(w * 16 + 16 + frow) * 136 + kt * 32 + fk];
        s0 = __builtin_amdgcn_mfma_f32_16x16x32_bf16(af, b0, s0, 0, 0, 0);
        s1 = __builtin_amdgcn_mfma_f32_16x16x32_bf16(af, b1, s1, 0, 0, 0);
    }

    // ---- bias + mask + softmax. C-layout: lane holds rows m=quad*4+r, col=frow.
    // key tile0: lk=16w+col (rel = col-16-m); tile1: lk=16w+16+col (rel = col-m).
    const float scl   = 0.088388347648318447f;   // 1/sqrt(128)
    const float slope = exp2f(-(float)(h + 1));
    const bool  lead  = (i0 == 0) && (w == 0);   // tile0 keys have ks<0 -> masked
    const int   col   = frow;
    float inv[4];
    #pragma unroll
    for (int r = 0; r < 4; ++r) {
        const int m = quad * 4 + r;
        float v0 = (col < m || lead) ? -1e30f : s0[r] * scl + slope * (float)(col - 16 - m);
        float v1 = (col > m)         ? -1e30f : s1[r] * scl + slope * (float)(col - m);
        float mx = fmaxf(v0, v1);
        #pragma unroll
        for (int off = 1; off < 16; off <<= 1) mx = fmaxf(mx, __shfl_xor(mx, off, 64));
        const float e0 = __expf(v0 - mx);
        const float e1 = __expf(v1 - mx);
        float sm = e0 + e1;
        #pragma unroll
        for (int off = 1; off < 16; off <<= 1) sm += __shfl_xor(sm, off, 64);
        inv[r] = 1.0f / sm;
        Plds[(w * 16 + m) * 40 + col]      = f2b(e0);
        Plds[(w * 16 + m) * 40 + 16 + col] = f2b(e1);
    }

    // ---- O = P V (A-frag of P from wave-private LDS; B-frag from Vt)
    const bf16x8 pf = *(const bf16x8*)&Plds[(w * 16 + frow) * 40 + fk];
    f32x4 oa[8];
    #pragma unroll
    for (int nt = 0; nt < 8; ++nt) {
        oa[nt][0] = 0.f; oa[nt][1] = 0.f; oa[nt][2] = 0.f; oa[nt][3] = 0.f;
        const bf16x8 vf = *(const bf16x8*)&Vt[(nt * 16 + frow) * 88 + w * 16 + fk];
        oa[nt] = __builtin_amdgcn_mfma_f32_16x16x32_bf16(pf, vf, oa[nt], 0, 0, 0);
    }

    // ---- epilogue: same lanes own the same rows -> apply inv[r] here
    #pragma unroll
    for (int nt = 0; nt < 8; ++nt)
        #pragma unroll
        for (int r = 0; r < 4; ++r) {
            const int m = quad * 4 + r;
            o[(size_t)(r0 + w * 16 + m) * DIM + h * HDIM + nt * 16 + col] =
                f2b(oa[nt][r] * inv[r]);
        }
}

// ---------------- launch ----------------
extern "C" void kernel_launch(void* const* d_in, const int* in_sizes, int n_in,
                              void* d_out, int out_size, void* d_ws, size_t ws_size,
                              hipStream_t stream)
{
    const float* x  = (const float*)d_in[0];
    const float* wq = (const float*)d_in[1];
    const float* wk = (const float*)d_in[2];
    const float* wv = (const float*)d_in[3];
    const float* wo = (const float*)d_in[4];
    const float* qw = (const float*)d_in[5];
    const float* kw = (const float*)d_in[6];
    float* out = (float*)d_out;

    // ws: xb 16MB | weights 8MB | xqkv 48MB | ob 16MB  (88MB; 96MB proven OK)
    unsigned short* xb   = (unsigned short*)d_ws;
    unsigned short* wb   = xb + (size_t)MROWS * DIM;              // wq|wk|wv|wo
    unsigned short* xqkv = wb + (size_t)4 * DIM * DIM;
    unsigned short* ob   = xqkv + (size_t)MROWS * QKVDIM;
    unsigned short* wob  = wb + (size_t)3 * DIM * DIM;

    cast_all<<<12288, 256, 0, stream>>>(x, wq, wk, wv, wo, xb, wb);

    // fused QKV projection: [8192,1024] x [3072,1024]^T
    gemm_nt_mfma<unsigned short><<<dim3(QKVDIM / 128, MROWS / 128), 256, 0, stream>>>(
        xb, wb, xqkv, MROWS, QKVDIM, DIM);

    rmsnorm2<<<dim3(MROWS, 2), 256, 0, stream>>>(xqkv, qw, kw);

    attn_mfma<<<dim3(MROWS / 64, NHEADS), 256, 0, stream>>>(xqkv, ob);

    gemm_nt_mfma<float><<<dim3(DIM / 128, MROWS / 128), 256, 0, stream>>>(
        ob, wob, out, MROWS, DIM, DIM);
}

// Round 5
// 218.398 us; speedup vs baseline: 5.2831x; 1.0506x over previous
//
#include <hip/hip_runtime.h>
#include <math.h>

// Problem constants (fixed by the reference)
#define NHEADS 8
#define HDIM   128
#define WIN    16
#define DIM    1024
#define QKVDIM 3072
#define SEQ    2048
#define BATCH  4
#define MROWS  (BATCH * SEQ)   // 8192
#define RMS_EPS 1e-6f

typedef __bf16 bf16x8 __attribute__((ext_vector_type(8)));
typedef unsigned short u16x8 __attribute__((ext_vector_type(8)));
typedef float  f32x4  __attribute__((ext_vector_type(4)));

// ---------------- bf16 bit helpers (RNE) ----------------
__device__ __forceinline__ unsigned short f2b(float f) {
    union { float f; unsigned u; } c; c.f = f;
    return (unsigned short)((c.u + 0x7FFFu + ((c.u >> 16) & 1u)) >> 16);
}
__device__ __forceinline__ float b2f(unsigned short u) {
    union { unsigned u; float f; } c; c.u = ((unsigned)u) << 16; return c.f;
}
__device__ __forceinline__ bf16x8 u2b(u16x8 u) {
    union { u16x8 u; bf16x8 b; } c; c.u = u; return c.b;
}

__device__ __forceinline__ void storec(unsigned short* p, float v) { *p = f2b(v); }
__device__ __forceinline__ void storec(float* p, float v) { *p = v; }

// ---------------- fused cast: x + 4 weights + zero sumsq ----------------
// blocks 0..8191: x -> xb. 8192..12287: weights -> wb. 12288..12303: zero sumsq.
__global__ __launch_bounds__(256) void cast_all(const float* __restrict__ x,
                                                const float* __restrict__ w0,
                                                const float* __restrict__ w1,
                                                const float* __restrict__ w2,
                                                const float* __restrict__ w3,
                                                unsigned short* __restrict__ xb,
                                                unsigned short* __restrict__ wb,
                                                float* __restrict__ sumsq)
{
    const int b = blockIdx.x;
    const int t = threadIdx.x;
    if (b >= 12288) {   // zero the 8192x2 f32 sumsq buffer (ws is poisoned 0xAA)
        ((float4*)sumsq)[(b - 12288) * 256 + t] = make_float4(0.f, 0.f, 0.f, 0.f);
        return;
    }
    const float* src;
    unsigned short* dst;
    int i;
    if (b < 8192) {
        i = b * 256 + t;
        src = x; dst = xb;
    } else {
        const int bb = b - 8192;
        const int which = bb >> 10;
        i = (bb & 1023) * 256 + t;
        src = which == 0 ? w0 : which == 1 ? w1 : which == 2 ? w2 : w3;
        dst = wb + (size_t)which * DIM * DIM;
    }
    const float4 v = ((const float4*)src)[i];
    ushort4 o;
    o.x = f2b(v.x); o.y = f2b(v.y); o.z = f2b(v.z); o.w = f2b(v.w);
    ((ushort4*)dst)[i] = o;
}

// ---------------- MFMA GEMM (NT): C[M,N] = A[M,K] * B[N,K]^T, bf16 in, fp32 acc ----------------
// 128x128 tile, BK=64, XOR-swizzled LDS [128][64]: element (r, chunk c of 8) lives at
// r*64 + (c ^ (r&7))*8. Swizzle applied on the GLOBAL address of global_load_lds
// (LDS side must stay base+lane*16 contiguous). Frag reads then hit 2-way banks (free).
// If sumsq != nullptr: epilogue accumulates per-row sum of squares for cols < 2048
// (q-range -> sumsq[row*2+0], k-range -> sumsq[row*2+1]) via 16-lane reduce + atomicAdd.
template <typename TC>
__global__ __launch_bounds__(256) void gemm_nt_mfma(const unsigned short* __restrict__ A,
                                                    const unsigned short* __restrict__ B,
                                                    TC* __restrict__ C,
                                                    float* __restrict__ sumsq,
                                                    int M, int N, int K)
{
    __shared__ __align__(16) __bf16 As[128 * 64];
    __shared__ __align__(16) __bf16 Bs[128 * 64];

    const int t    = threadIdx.x;
    const int w    = t >> 6;
    const int lane = t & 63;
    const int wm   = w >> 1;
    const int wn   = w & 1;
    const int bm0  = blockIdx.y * 128;
    const int bn0  = blockIdx.x * 128;

    // staging: one instr = 8 rows x 128B. lane l -> local row l>>3, lds chunk l&7,
    // global chunk (l&7) ^ ((l>>3)&7)  [row&7 == (l>>3)&7 since segments are 8-aligned]
    const int lrow   = lane >> 3;
    const int lchunk = (lane & 7) ^ (lrow & 7);
    const size_t laneoff = (size_t)lrow * K + lchunk * 8;

    const unsigned short* gA = A + (size_t)bm0 * K + laneoff;
    const unsigned short* gB = B + (size_t)bn0 * K + laneoff;

    const int frow = lane & 15;
    const int quad = lane >> 4;
    // swizzled chunk byte-offsets for sub-steps 0/1 (chunk index sub*4+quad)
    const int cs0 = ((quad    ) ^ (frow & 7)) * 8;
    const int cs1 = ((quad + 4) ^ (frow & 7)) * 8;

    f32x4 acc[4][4];
    #pragma unroll
    for (int i = 0; i < 4; ++i)
        #pragma unroll
        for (int j = 0; j < 4; ++j)
            #pragma unroll
            for (int e = 0; e < 4; ++e) acc[i][j][e] = 0.f;

    for (int kt = 0; kt < K; kt += 64) {
        __syncthreads();   // previous iteration's ds_reads retired before overwrite
        #pragma unroll
        for (int s = 0; s < 4; ++s) {
            const int seg = w * 4 + s;   // 16 segments x 8 rows = 128 rows
            __builtin_amdgcn_global_load_lds(
                (const __attribute__((address_space(1))) void*)(gA + (size_t)seg * 8 * K + kt),
                (__attribute__((address_space(3))) void*)&As[seg * 512], 16, 0, 0);
            __builtin_amdgcn_global_load_lds(
                (const __attribute__((address_space(1))) void*)(gB + (size_t)seg * 8 * K + kt),
                (__attribute__((address_space(3))) void*)&Bs[seg * 512], 16, 0, 0);
        }
        __syncthreads();   // tile resident

        #pragma unroll
        for (int sub = 0; sub < 2; ++sub) {
            const int cs = sub ? cs1 : cs0;
            bf16x8 af[4], bg[4];
            #pragma unroll
            for (int i = 0; i < 4; ++i) {
                af[i] = *(const bf16x8*)&As[(wm * 64 + i * 16 + frow) * 64 + cs];
                bg[i] = *(const bf16x8*)&Bs[(wn * 64 + i * 16 + frow) * 64 + cs];
            }
            #pragma unroll
            for (int i = 0; i < 4; ++i)
                #pragma unroll
                for (int j = 0; j < 4; ++j)
                    acc[i][j] = __builtin_amdgcn_mfma_f32_16x16x32_bf16(af[i], bg[j], acc[i][j], 0, 0, 0);
        }
    }

    // epilogue: C/D layout col=lane&15, row=(lane>>4)*4+reg
    const int m_base = bm0 + wm * 64;
    const int n_base = bn0 + wn * 64;
    const int col    = frow;
    const int rquad  = quad * 4;
    #pragma unroll
    for (int i = 0; i < 4; ++i)
        #pragma unroll
        for (int r = 0; r < 4; ++r) {
            TC* crow = C + (size_t)(m_base + i * 16 + rquad + r) * N + n_base + col;
            #pragma unroll
            for (int j = 0; j < 4; ++j)
                storec(crow + j * 16, acc[i][j][r]);
        }

    if (sumsq != nullptr && bn0 < 2 * DIM) {
        const int which = bn0 >> 10;   // 0 = q cols, 1 = k cols (128 | 1024)
        #pragma unroll
        for (int i = 0; i < 4; ++i)
            #pragma unroll
            for (int r = 0; r < 4; ++r) {
                float p = acc[i][0][r] * acc[i][0][r] + acc[i][1][r] * acc[i][1][r]
                        + acc[i][2][r] * acc[i][2][r] + acc[i][3][r] * acc[i][3][r];
                p += __shfl_xor(p, 1, 64);
                p += __shfl_xor(p, 2, 64);
                p += __shfl_xor(p, 4, 64);
                p += __shfl_xor(p, 8, 64);
                if (frow == 0)
                    atomicAdd(&sumsq[(size_t)(m_base + i * 16 + rquad + r) * 2 + which], p);
            }
    }
}

// ---------------- MFMA sliding-window attention, RMSNorm fused on load ----------------
// grid (MROWS/64, NHEADS). Block: 64 queries x 1 head, 4 waves x 16 queries.
// Q/K are normalized on the fly: val * rsqrt(sumsq/1024 + eps) * w[col].
__global__ __launch_bounds__(256) void attn_mfma(const unsigned short* __restrict__ qkv,
                                                 const float* __restrict__ sumsq,
                                                 const float* __restrict__ qw,
                                                 const float* __restrict__ kw,
                                                 unsigned short* __restrict__ o)
{
    __shared__ __align__(16) unsigned short Klds[80 * 136];
    __shared__ __align__(16) unsigned short Vt[128 * 88];
    __shared__ __align__(16) unsigned short Plds[4 * 16 * 40];

    const int t  = threadIdx.x;
    const int qb = blockIdx.x;
    const int h  = blockIdx.y;
    const int r0 = qb * 64;             // first query's global row
    const int i0 = r0 & (SEQ - 1);      // seq-local (block never spans batches)
    const int bb = r0 - i0;             // batch base row

    const unsigned short* kg = qkv + DIM + h * HDIM;
    const unsigned short* vg = qkv + 2 * DIM + h * HDIM;

    #pragma unroll
    for (int it = 0; it < 5; ++it) {
        const int c = it * 256 + t;
        {   // K: row-major chunk map; normalize while staging
            const int lr = c >> 4, c8 = c & 15;
            const int ks = i0 - 16 + lr;
            const int rc = ks < 0 ? 0 : ks;          // clamped rows masked later
            const float ksc = rsqrtf(sumsq[(size_t)(bb + rc) * 2 + 1] * (1.0f / DIM) + RMS_EPS);
            const u16x8 kv = *(const u16x8*)(kg + (size_t)(bb + rc) * QKVDIM + c8 * 8);
            u16x8 ko;
            #pragma unroll
            for (int e = 0; e < 8; ++e)
                ko[e] = f2b(b2f(kv[e]) * ksc * kw[h * HDIM + c8 * 8 + e]);
            *(u16x8*)&Klds[lr * 136 + c8 * 8] = ko;
        }
        {   // V: key-consecutive chunk map -> transposed scatter (no norm)
            const int c8 = c / 80, lr = c - c8 * 80;
            const int ks = i0 - 16 + lr;
            const int rc = ks < 0 ? 0 : ks;
            const u16x8 vv = *(const u16x8*)(vg + (size_t)(bb + rc) * QKVDIM + c8 * 8);
            #pragma unroll
            for (int e = 0; e < 8; ++e)
                Vt[(c8 * 8 + e) * 88 + lr] = vv[e];
        }
    }
    __syncthreads();

    const int w    = t >> 6;
    const int lane = t & 63;
    const int frow = lane & 15;
    const int quad = lane >> 4;
    const int fk   = quad * 8;

    // ---- S = Q K^T; Q normalized on load
    f32x4 s0 = {0.f, 0.f, 0.f, 0.f}, s1 = {0.f, 0.f, 0.f, 0.f};
    const unsigned short* qg = qkv + h * HDIM;
    const size_t qrow = (size_t)(r0 + w * 16 + frow) * QKVDIM;
    const float qsc = rsqrtf(sumsq[(size_t)(r0 + w * 16 + frow) * 2] * (1.0f / DIM) + RMS_EPS);
    #pragma unroll
    for (int kt = 0; kt < 4; ++kt) {
        const u16x8 qa = *(const u16x8*)(qg + qrow + kt * 32 + fk);
        u16x8 qn;
        #pragma unroll
        for (int e = 0; e < 8; ++e)
            qn[e] = f2b(b2f(qa[e]) * qsc * qw[h * HDIM + kt * 32 + fk + e]);
        const bf16x8 af = u2b(qn);
        const bf16x8 b0 = *(const bf16x8*)&Klds[(w * 16 + frow) * 136 + kt * 32 + fk];
        const bf16x8 b1 = *(const bf16x8*)&Klds[(w * 16 + 16 + frow) * 136 + kt * 32 + fk];
        s0 = __builtin_amdgcn_mfma_f32_16x16x32_bf16(af, b0, s0, 0, 0, 0);
        s1 = __builtin_amdgcn_mfma_f32_16x16x32_bf16(af, b1, s1, 0, 0, 0);
    }

    // ---- bias + mask + softmax (C-layout: rows m=quad*4+r, col=frow)
    const float scl   = 0.088388347648318447f;   // 1/sqrt(128)
    const float slope = exp2f(-(float)(h + 1));
    const bool  lead  = (i0 == 0) && (w == 0);
    const int   col   = frow;
    float inv[4];
    #pragma unroll
    for (int r = 0; r < 4; ++r) {
        const int m = quad * 4 + r;
        float v0 = (col < m || lead) ? -1e30f : s0[r] * scl + slope * (float)(col - 16 - m);
        float v1 = (col > m)         ? -1e30f : s1[r] * scl + slope * (float)(col - m);
        float mx = fmaxf(v0, v1);
        #pragma unroll
        for (int off = 1; off < 16; off <<= 1) mx = fmaxf(mx, __shfl_xor(mx, off, 64));
        const float e0 = __expf(v0 - mx);
        const float e1 = __expf(v1 - mx);
        float sm = e0 + e1;
        #pragma unroll
        for (int off = 1; off < 16; off <<= 1) sm += __shfl_xor(sm, off, 64);
        inv[r] = 1.0f / sm;
        Plds[(w * 16 + m) * 40 + col]      = f2b(e0);
        Plds[(w * 16 + m) * 40 + 16 + col] = f2b(e1);
    }

    // ---- O = P V
    const bf16x8 pf = *(const bf16x8*)&Plds[(w * 16 + frow) * 40 + fk];
    f32x4 oa[8];
    #pragma unroll
    for (int nt = 0; nt < 8; ++nt) {
        oa[nt][0] = 0.f; oa[nt][1] = 0.f; oa[nt][2] = 0.f; oa[nt][3] = 0.f;
        const bf16x8 vf = *(const bf16x8*)&Vt[(nt * 16 + frow) * 88 + w * 16 + fk];
        oa[nt] = __builtin_amdgcn_mfma_f32_16x16x32_bf16(pf, vf, oa[nt], 0, 0, 0);
    }

    #pragma unroll
    for (int nt = 0; nt < 8; ++nt)
        #pragma unroll
        for (int r = 0; r < 4; ++r) {
            const int m = quad * 4 + r;
            o[(size_t)(r0 + w * 16 + m) * DIM + h * HDIM + nt * 16 + col] =
                f2b(oa[nt][r] * inv[r]);
        }
}

// ---------------- launch ----------------
extern "C" void kernel_launch(void* const* d_in, const int* in_sizes, int n_in,
                              void* d_out, int out_size, void* d_ws, size_t ws_size,
                              hipStream_t stream)
{
    const float* x  = (const float*)d_in[0];
    const float* wq = (const float*)d_in[1];
    const float* wk = (const float*)d_in[2];
    const float* wv = (const float*)d_in[3];
    const float* wo = (const float*)d_in[4];
    const float* qw = (const float*)d_in[5];
    const float* kw = (const float*)d_in[6];
    float* out = (float*)d_out;

    // ws: xb 16MB | weights 8MB | xqkv 48MB | ob 16MB | sumsq 64KB  (~88MB)
    unsigned short* xb   = (unsigned short*)d_ws;
    unsigned short* wb   = xb + (size_t)MROWS * DIM;              // wq|wk|wv|wo
    unsigned short* xqkv = wb + (size_t)4 * DIM * DIM;
    unsigned short* ob   = xqkv + (size_t)MROWS * QKVDIM;
    float*          ssq  = (float*)(ob + (size_t)MROWS * DIM);
    unsigned short* wob  = wb + (size_t)3 * DIM * DIM;

    cast_all<<<12304, 256, 0, stream>>>(x, wq, wk, wv, wo, xb, wb, ssq);

    gemm_nt_mfma<unsigned short><<<dim3(QKVDIM / 128, MROWS / 128), 256, 0, stream>>>(
        xb, wb, xqkv, ssq, MROWS, QKVDIM, DIM);

    attn_mfma<<<dim3(MROWS / 64, NHEADS), 256, 0, stream>>>(xqkv, ssq, qw, kw, ob);

    gemm_nt_mfma<float><<<dim3(DIM / 128, MROWS / 128), 256, 0, stream>>>(
        ob, wob, out, nullptr, MROWS, DIM, DIM);
}